// Round 11
// baseline (166.083 us; speedup 1.0000x reference)
//
#include <hip/hip_runtime.h>

// ============================================================================
// FusedConv: per-edge MLP (32->256->256->768-slice) + small tensor contraction.
// bf16 MFMA (16x16x32) for the three GEMMs, fp32 accumulate, fused per
// 64-edge tile through LDS.
//
// Round-11: identical resubmission of round-10 (container acquire failed
// twice — infra, not kernel; source audited clean: bounds, static bb[]
// indexing under full unroll, LDS extents match round-9's passing run).
//
// Round-10, two changes on the round-9 base (91.5us fused / 162.6 total):
//  1) PREP REWRITE (tests the session-long ~65us dur_us-vs-fused gap, which
//     is data-size-invariant => prep latency, not throughput). Old prep: 270K
//     threads x one scalar 2B scattered store (16B-stride partial lines).
//     New prep: 33792 threads x one coalesced 16B store (8 scattered dword
//     reads of L2-resident weights), 132 blocks.
//  2) DEPTH-2 B-PREFETCH in G2/G3. Old: depth-1 (load at ks, use at ks+1,
//     ~55cy slack vs ~250cy L2 latency -> ~200cy stall/iter, ~8-10Kcy/wave).
//     New: rotating bb[3][nt] triple-buffer, statically indexed under full
//     unroll (no dynamic-index scratch); G3 also preloads next-o ks0+ks1
//     under the epilogue. +16 arch VGPR (64->~80), total <=128 keeps
//     4 waves/SIMD under __launch_bounds__(512,4).
//
// LDS map (81920 B, 2 blocks/CU = exactly 160KB):
//   hS    [    0..32768): h1 then h2, 64 rows x 512 B, 16B-chunk xor swizzle
//   tmpS  [32768..57344): tmp[J=48][e=64][4] bf16 (d=3 + pad)
//   auxS  [57344..81920): staging featsb[64][50]+basisb[64][27] (phase A),
//                         then per-wave rp[48 J][32 e] bf16 w/ swizzle (B)
// ============================================================================

typedef __bf16 bf16x8 __attribute__((ext_vector_type(8)));
typedef __bf16 bf16x4 __attribute__((ext_vector_type(4)));
typedef float f32x4 __attribute__((ext_vector_type(4)));

#define TE 64
#define E_TOT 65536

__device__ __forceinline__ f32x4 mfma16(bf16x8 a, bf16x8 b, f32x4 c) {
    return __builtin_amdgcn_mfma_f32_16x16x32_bf16(a, b, c, 0, 0, 0);
}

__device__ __forceinline__ float gelu_f(float x) {
    // tanh-form GELU via exp2; branchless, 2 transcendentals.
    float u = x * x;
    float t = x * fmaf(u, 0.10294345f, 2.3022082f);
    return x * __builtin_amdgcn_rcpf(1.0f + __builtin_amdgcn_exp2f(-t));
}

// ---- ws layout (bytes): fragment-ordered weights ----
// Fragment for tile t (cols 16t..16t+15), k-step ks: lane l holds
// B[k = ks*32 + (l>>4)*8 + j][col = 16t + (l&15)], j=0..7.
#define WS_W1F 0u        // 16 t x 64 x 8 bf16          16384 B
#define WS_W2F 16384u    // 16 t x 8 ks x 64 x 8       131072 B
#define WS_W3F 147456u   // 48 t x 8 ks x 64 x 8       393216 B

#define N_W1F 8192
#define N_W2F 65536
#define N_W3F 196608
#define PREP_TOT (N_W1F + N_W2F + N_W3F)
#define PREP_V  (PREP_TOT / 8)     // 33792 threads, one bf16x8 store each

__global__ __launch_bounds__(256) void prep_kernel(
    const float* __restrict__ W1, const float* __restrict__ W2,
    const float* __restrict__ W3,
    __bf16* __restrict__ W1F, __bf16* __restrict__ W2F,
    __bf16* __restrict__ W3F)
{
    int v = blockIdx.x * blockDim.x + threadIdx.x;
    if (v >= PREP_V) return;
    bf16x8 o8;
    if (v < (N_W1F >> 3)) {
        // W1F[((t*64 + q*16 + cc)<<3) + j], k = q*8+j, col = t*16+cc
        int t = v >> 6, rem = v & 63, q = rem >> 4, cc = rem & 15;
        int col = t * 16 + cc;
        #pragma unroll
        for (int j = 0; j < 8; ++j)
            o8[j] = (__bf16)W1[(q * 8 + j) * 256 + col];
        *(bf16x8*)(W1F + ((size_t)v << 3)) = o8;
    } else if (v < ((N_W1F + N_W2F) >> 3)) {
        int v2 = v - (N_W1F >> 3);
        // W2F[(((t*8+ks)*64 + q*16 + cc)<<3) + j], k = ks*32+q*8+j
        int u = v2 >> 6, t = u >> 3, ks = u & 7;
        int rem = v2 & 63, q = rem >> 4, cc = rem & 15;
        int col = t * 16 + cc;
        #pragma unroll
        for (int j = 0; j < 8; ++j)
            o8[j] = (__bf16)W2[(ks * 32 + q * 8 + j) * 256 + col];
        *(bf16x8*)(W2F + ((size_t)v2 << 3)) = o8;
    } else {
        int v3 = v - ((N_W1F + N_W2F) >> 3);
        // W3F[(((t*8+ks)*64 + q*16 + cc)<<3) + j], src col = t*16+cc in 768-slice
        int u = v3 >> 6, t = u >> 3, ks = u & 7;
        int rem = v3 & 63, q = rem >> 4, cc = rem & 15;
        int col = t * 16 + cc;
        #pragma unroll
        for (int j = 0; j < 8; ++j)
            o8[j] = (__bf16)W3[(ks * 32 + q * 8 + j) * 1536 + 768 + col];
        *(bf16x8*)(W3F + ((size_t)v3 << 3)) = o8;
    }
}

// A-frag layout: lane holds A[m=lane&15][k=(lane>>4)*8 + j], j=0..7
// B-frag layout: lane holds B[k=(lane>>4)*8 + j][n=lane&15]
// C/D layout:    element (row=(lane>>4)*4 + reg, col=lane&15)
__global__ __launch_bounds__(512, 4) void fused_kernel(
    const float* __restrict__ edges, const __bf16* __restrict__ W1F,
    const __bf16* __restrict__ W2F, const __bf16* __restrict__ W3F,
    const float* __restrict__ b1, const float* __restrict__ b2,
    const float* __restrict__ feats, const float* __restrict__ basis,
    float* __restrict__ out)
{
    __shared__ __align__(16) unsigned char smem[81920];
    unsigned char* hS   = smem;             // 32768 B: h1, then h2 (64 rows)
    unsigned char* tmpS = smem + 32768;     // 24576 B: tmp[J][e][4] bf16
    unsigned char* auxS = smem + 57344;     // 24576 B: staging / per-wave rp
    __bf16* featsb = (__bf16*)auxS;           // [64][50] padded (6400 B)
    __bf16* basisb = (__bf16*)(auxS + 6400);  // [64][27]        (3456 B)

    const int tid = threadIdx.x;
    const int w  = tid >> 6;      // wave 0..7
    const int l  = tid & 63;
    const int c  = l & 15;
    const int q  = l >> 4;        // 0..3
    const int wn = w & 3;         // col-block 0..3
    const int mh = w >> 2;        // m-half 0..1 (edges mh*32 .. mh*32+31)
    const int eb = blockIdx.x * TE;
    const int ebase = mh * 32;    // wave's local edge base

    const f32x4 zero = {0.f, 0.f, 0.f, 0.f};

    // ---- stage feats/basis into aux (issue global loads early) -------------
    #pragma unroll
    for (int it = 0; it < 6; ++it) {
        int idx = tid + it * 512;             // 0..3071
        int e = idx / 48, r = idx - e * 48;
        featsb[e * 50 + r] = (__bf16)feats[(size_t)eb * 48 + idx];
    }
    #pragma unroll
    for (int it = 0; it < 4; ++it) {
        int idx = tid + it * 512;             // 0..2047 (need 1728)
        if (idx < 1728) basisb[idx] = (__bf16)basis[(size_t)eb * 27 + idx];
    }

    // ---------------- G1: h1 = gelu(edges @ W1 + b1), K=32 ------------------
    const float* er0 = edges + (size_t)(eb + ebase + c) * 32 + q * 8;
    const float* er1 = edges + (size_t)(eb + ebase + 16 + c) * 32 + q * 8;
    f32x4 e00 = *(const f32x4*)er0;
    f32x4 e01 = *(const f32x4*)(er0 + 4);
    f32x4 e10 = *(const f32x4*)er1;
    f32x4 e11 = *(const f32x4*)(er1 + 4);
    bf16x8 a0, a1;
    #pragma unroll
    for (int j = 0; j < 4; ++j) {
        a0[j] = (__bf16)e00[j]; a0[j + 4] = (__bf16)e01[j];
        a1[j] = (__bf16)e10[j]; a1[j + 4] = (__bf16)e11[j];
    }

    f32x4 acc1[2][4];
    #pragma unroll
    for (int mt = 0; mt < 2; ++mt)
        #pragma unroll
        for (int nt = 0; nt < 4; ++nt) acc1[mt][nt] = zero;

    const __bf16* W1Fw = W1F + (size_t)(wn * 4) * 512 + (size_t)l * 8;
    #pragma unroll
    for (int nt = 0; nt < 4; ++nt) {
        bf16x8 bf = *(const bf16x8*)(W1Fw + nt * 512);
        acc1[0][nt] = mfma16(a0, bf, acc1[0][nt]);
        acc1[1][nt] = mfma16(a1, bf, acc1[1][nt]);
    }
    #pragma unroll
    for (int nt = 0; nt < 4; ++nt) {
        int col = wn * 64 + nt * 16 + c;
        float bias = b1[col];
        #pragma unroll
        for (int mt = 0; mt < 2; ++mt)
            #pragma unroll
            for (int r = 0; r < 4; ++r) {
                int e = ebase + mt * 16 + q * 4 + r;
                float g = gelu_f(acc1[mt][nt][r] + bias);
                int chunk = (col >> 3) ^ (e & 7);
                *(__bf16*)(hS + e * 512 + chunk * 16 + (col & 7) * 2) = (__bf16)g;
            }
    }
    __syncthreads();   // S1: h1 + staged feats/basis visible

    // ---------------- G2: h2 = gelu(h1 @ W2 + b2), K=256 --------------------
    // depth-2 rotating triple-buffer for B (statically indexed, full unroll)
    f32x4 acc2[2][4];
    #pragma unroll
    for (int mt = 0; mt < 2; ++mt)
        #pragma unroll
        for (int nt = 0; nt < 4; ++nt) acc2[mt][nt] = zero;

    const __bf16* W2Fw = W2F + (size_t)(wn * 4) * 4096 + (size_t)l * 8;
    {
        bf16x8 bb[3][4];
        #pragma unroll
        for (int nt = 0; nt < 4; ++nt) {
            bb[0][nt] = *(const bf16x8*)(W2Fw + nt * 4096);
            bb[1][nt] = *(const bf16x8*)(W2Fw + nt * 4096 + 512);
        }
        #pragma unroll
        for (int ks = 0; ks < 8; ++ks) {
            if (ks < 6) {
                #pragma unroll
                for (int nt = 0; nt < 4; ++nt)
                    bb[(ks + 2) % 3][nt] =
                        *(const bf16x8*)(W2Fw + nt * 4096 + (ks + 2) * 512);
            }
            bf16x8 af0, af1;
            { int m = ebase + c;      int chunk = (ks * 4 + q) ^ (m & 7); af0 = *(const bf16x8*)(hS + m * 512 + chunk * 16); }
            { int m = ebase + 16 + c; int chunk = (ks * 4 + q) ^ (m & 7); af1 = *(const bf16x8*)(hS + m * 512 + chunk * 16); }
            #pragma unroll
            for (int nt = 0; nt < 4; ++nt) {
                acc2[0][nt] = mfma16(af0, bb[ks % 3][nt], acc2[0][nt]);
                acc2[1][nt] = mfma16(af1, bb[ks % 3][nt], acc2[1][nt]);
            }
        }
    }

    // ------- build tmp[J][e][4] bf16 from staged feats/basis ----------------
    // thread owns edge e = tid&63, J = (tid>>6) + 8k, k=0..5; writes b64.
    {
        int e = tid & 63;
        int j0 = tid >> 6;
        const __bf16* fr = featsb + e * 50;
        const __bf16* br = basisb + e * 27;
        #pragma unroll
        for (int k2 = 0; k2 < 6; ++k2) {
            int J = j0 + k2 * 8;
            int i0 = J / 3;
            int nf = J - i0 * 3;
            float f0 = (float)fr[i0 * 3 + 0];
            float f1 = (float)fr[i0 * 3 + 1];
            float f2 = (float)fr[i0 * 3 + 2];
            const __bf16* bp = br + nf * 3;
            bf16x4 v;
            #pragma unroll
            for (int d = 0; d < 3; ++d) {
                float s = f0 * (float)bp[d] + f1 * (float)bp[9 + d] + f2 * (float)bp[18 + d];
                v[d] = (__bf16)s;
            }
            v[3] = (__bf16)0.f;
            *(bf16x4*)(tmpS + J * 512 + e * 8) = v;
        }
    }
    __syncthreads();   // S2: all h1 reads done (safe to overwrite with h2)

    #pragma unroll
    for (int nt = 0; nt < 4; ++nt) {
        int col = wn * 64 + nt * 16 + c;
        float bias = b2[col];
        #pragma unroll
        for (int mt = 0; mt < 2; ++mt)
            #pragma unroll
            for (int r = 0; r < 4; ++r) {
                int e = ebase + mt * 16 + q * 4 + r;
                float g = gelu_f(acc2[mt][nt][r] + bias);
                int chunk = (col >> 3) ^ (e & 7);
                *(__bf16*)(hS + e * 512 + chunk * 16 + (col & 7) * 2) = (__bf16)g;
            }
    }

    // prefetch first o's ks0 AND ks1 fragments (global, no barrier dependency)
    const __bf16* W3Fl = W3F + (size_t)l * 8;
    bf16x8 pre0[3], pre1[3];
    #pragma unroll
    for (int nt = 0; nt < 3; ++nt) {
        pre0[nt] = *(const bf16x8*)(W3Fl + (size_t)((wn * 4) * 3 + nt) * 4096);
        pre1[nt] = *(const bf16x8*)(W3Fl + (size_t)((wn * 4) * 3 + nt) * 4096 + 512);
    }

    __syncthreads();   // S3: h2 + tmp visible; aux staging dead from here on

    // ------- G3 (rp = h2 @ W3k) fused with final contraction, per o ----------
    unsigned char* rb = auxS + w * 3072;   // per-wave rp[48 J][32 e] bf16
    const int le = l & 31, hv = l >> 5;

    #pragma unroll 1
    for (int oi = 0; oi < 4; ++oi) {
        int o = wn * 4 + oi;          // wave owns o in {4*wn..4*wn+3}
        const __bf16* W3Fo = W3Fl + (size_t)(o * 3) * 4096;
        f32x4 acc3[2][3];
        #pragma unroll
        for (int mt = 0; mt < 2; ++mt)
            #pragma unroll
            for (int nt = 0; nt < 3; ++nt) acc3[mt][nt] = zero;

        // rotating depth-2 buffer seeded from the cross-o prefetch pair
        bf16x8 bb[3][3];
        #pragma unroll
        for (int nt = 0; nt < 3; ++nt) { bb[0][nt] = pre0[nt]; bb[1][nt] = pre1[nt]; }

        #pragma unroll
        for (int ks = 0; ks < 8; ++ks) {
            if (ks < 6) {
                #pragma unroll
                for (int nt = 0; nt < 3; ++nt)
                    bb[(ks + 2) % 3][nt] =
                        *(const bf16x8*)(W3Fo + nt * 4096 + (ks + 2) * 512);
            }
            bf16x8 af0, af1;
            { int m = ebase + c;      int chunk = (ks * 4 + q) ^ (m & 7); af0 = *(const bf16x8*)(hS + m * 512 + chunk * 16); }
            { int m = ebase + 16 + c; int chunk = (ks * 4 + q) ^ (m & 7); af1 = *(const bf16x8*)(hS + m * 512 + chunk * 16); }
            #pragma unroll
            for (int nt = 0; nt < 3; ++nt) {
                acc3[0][nt] = mfma16(af0, bb[ks % 3][nt], acc3[0][nt]);
                acc3[1][nt] = mfma16(af1, bb[ks % 3][nt], acc3[1][nt]);
            }
        }
        // prefetch next o's ks0+ks1; in flight during the epilogue below
        {
            int on = (oi < 3) ? (o + 1) : o;
            #pragma unroll
            for (int nt = 0; nt < 3; ++nt) {
                pre0[nt] = *(const bf16x8*)(W3Fl + (size_t)(on * 3 + nt) * 4096);
                pre1[nt] = *(const bf16x8*)(W3Fl + (size_t)(on * 3 + nt) * 4096 + 512);
            }
        }
        // spill rp tile (32e x 48J) as bf16x4 swizzled b64 writes
        #pragma unroll
        for (int nt = 0; nt < 3; ++nt) {
            int J = nt * 16 + c;
            #pragma unroll
            for (int mt = 0; mt < 2; ++mt) {
                bf16x4 v;
                v[0] = (__bf16)acc3[mt][nt][0];
                v[1] = (__bf16)acc3[mt][nt][1];
                v[2] = (__bf16)acc3[mt][nt][2];
                v[3] = (__bf16)acc3[mt][nt][3];
                *(bf16x4*)(rb + J * 64 + (((mt * 4 + q) ^ (J & 7)) << 3)) = v;
            }
        }
        // IR-order fence: reads below stay below the spills (same-wave DS).
        asm volatile("" ::: "memory");

        // out[e][o][d] = sum_J rp[e][J]*tmp[J][e][d]; 2 lanes per edge.
        float s0 = 0.f, s1 = 0.f, s2 = 0.f;
        #pragma unroll
        for (int jj = 0; jj < 24; ++jj) {
            int J = hv * 24 + jj;
            float rv = (float)*(const __bf16*)(rb + J * 64 +
                           ((((le >> 2) ^ (J & 7)) << 3)) + (le & 3) * 2);
            bf16x4 tv = *(const bf16x4*)(tmpS + J * 512 + (ebase + le) * 8);
            s0 = fmaf(rv, (float)tv[0], s0);
            s1 = fmaf(rv, (float)tv[1], s1);
            s2 = fmaf(rv, (float)tv[2], s2);
        }
        // fence: next oi's spills stay below these reads.
        asm volatile("" ::: "memory");
        s0 += __shfl_xor(s0, 32, 64);
        s1 += __shfl_xor(s1, 32, 64);
        s2 += __shfl_xor(s2, 32, 64);
        if (hv == 0) {
            float* op_ptr = out + (size_t)(eb + ebase + le) * 48 + o * 3;
            op_ptr[0] = s0; op_ptr[1] = s1; op_ptr[2] = s2;
        }
    }
}

extern "C" void kernel_launch(void* const* d_in, const int* in_sizes, int n_in,
                              void* d_out, int out_size, void* d_ws, size_t ws_size,
                              hipStream_t stream) {
    const float* edges = (const float*)d_in[0];
    const float* feats = (const float*)d_in[1];
    const float* basis = (const float*)d_in[2];
    const float* W1    = (const float*)d_in[3];
    const float* b1    = (const float*)d_in[4];
    const float* W2    = (const float*)d_in[5];
    const float* b2    = (const float*)d_in[6];
    const float* W3    = (const float*)d_in[7];
    float* out = (float*)d_out;

    __bf16* W1F = (__bf16*)((char*)d_ws + WS_W1F);
    __bf16* W2F = (__bf16*)((char*)d_ws + WS_W2F);
    __bf16* W3F = (__bf16*)((char*)d_ws + WS_W3F);

    prep_kernel<<<(PREP_V + 255) / 256, 256, 0, stream>>>(W1, W2, W3, W1F, W2F, W3F);
    fused_kernel<<<E_TOT / TE, 512, 0, stream>>>(edges, W1F, W2F, W3F, b1, b2,
                                                 feats, basis, out);
}